// Round 1
// baseline (482.289 us; speedup 1.0000x reference)
//
#include <hip/hip_runtime.h>
#include <math.h>

#define B_  32
#define A_  8400
#define G_  50
#define NC_ 80

struct AInfo { int lvl; int within; int w; int hw; float s; int x; int y; };

__device__ __forceinline__ AInfo anchor_info(int a) {
  AInfo r;
  if (a < 6400)      { r.lvl = 0; r.within = a;        r.w = 80; r.hw = 6400; r.s = 8.0f;  }
  else if (a < 8000) { r.lvl = 1; r.within = a - 6400; r.w = 40; r.hw = 1600; r.s = 16.0f; }
  else               { r.lvl = 2; r.within = a - 8000; r.w = 20; r.hw = 400;  r.s = 32.0f; }
  r.x = r.within % r.w; r.y = r.within / r.w;
  return r;
}

__device__ __forceinline__ float sigmoidf_(float x) { return 1.0f / (1.0f + expf(-x)); }

// Shared cost function. __noinline__ so kernels B and C produce bitwise-identical
// cost values (the threshold comparison cost <= thr must be consistent between them).
__device__ __attribute__((noinline)) float2 cost_iou_fn(
    float gx, float gy, float gw, float gh, int gcls,
    float cx, float cy, float st,
    float4 bx, float ssum, float sobj,
    const float* clsq, int hw)
{
  bool in_box = (cx > gx - 0.5f*gw) && (cx < gx + 0.5f*gw) &&
                (cy > gy - 0.5f*gh) && (cy < gy + 0.5f*gh);
  float rs = 2.5f * st;
  bool in_ctr = (fabsf(cx - gx) < rs) && (fabsf(cy - gy) < rs);
  bool geom = in_box && in_ctr;
  // pairwise IoU (gt vs decoded box)
  float tlx = fmaxf(gx - gw*0.5f, bx.x - bx.z*0.5f);
  float tly = fmaxf(gy - gh*0.5f, bx.y - bx.w*0.5f);
  float brx = fminf(gx + gw*0.5f, bx.x + bx.z*0.5f);
  float bry = fminf(gy + gh*0.5f, bx.y + bx.w*0.5f);
  bool en = (tlx < brx) && (tly < bry);
  float inter = en ? (brx - tlx) * (bry - tly) : 0.0f;
  float iou = inter / (gw*gh + bx.z*bx.w - inter + 1e-12f);
  float iou_cost = -logf(iou + 1e-8f);
  // cls cost
  float sc = sigmoidf_(clsq[(size_t)gcls * hw]);
  float p = sqrtf(sc * sobj);
  p = fminf(fmaxf(p, 1e-7f), (float)(1.0 - 1e-6));
  float cls_cost = -logf(p) + log1pf(-p) - ssum;
  float cost = cls_cost + 3.0f * iou_cost;
  if (!geom) cost += 100000.0f;
  return make_float2(cost, iou);
}

__global__ __launch_bounds__(256)
void kA_decode(const float* __restrict__ o0, const float* __restrict__ o1,
               const float* __restrict__ o2, const float* __restrict__ labels,
               float4* __restrict__ boxw, float* __restrict__ sobjw,
               float* __restrict__ ssumw, float* __restrict__ objlw,
               float* __restrict__ fgw)
{
  __shared__ float lab[G_*5];
  int b = blockIdx.y;
  for (int i = threadIdx.x; i < G_*5; i += 256) lab[i] = labels[b*G_*5 + i];
  __syncthreads();
  int a = blockIdx.x*256 + threadIdx.x;
  if (a >= A_) return;
  AInfo ai = anchor_info(a);
  const float* base = (ai.lvl==0) ? o0 : (ai.lvl==1 ? o1 : o2);
  base += (size_t)b * 85 * ai.hw + ai.within;
  float v0 = base[0];
  float v1 = base[(size_t)1*ai.hw];
  float v2 = base[(size_t)2*ai.hw];
  float v3 = base[(size_t)3*ai.hw];
  float v4 = base[(size_t)4*ai.hw];
  float4 bx;
  bx.x = (v0 + (float)ai.x) * ai.s;
  bx.y = (v1 + (float)ai.y) * ai.s;
  bx.z = expf(v2) * ai.s;
  bx.w = expf(v3) * ai.s;
  float so = sigmoidf_(v4);
  float cx = ((float)ai.x + 0.5f) * ai.s;
  float cy = ((float)ai.y + 0.5f) * ai.s;
  bool anyfg = false;
  for (int g = 0; g < G_; g++) {
    const float* L = &lab[g*5];
    float s5 = L[0]+L[1]+L[2]+L[3]+L[4];
    if (!(s5 > 0.0f)) continue;
    float gx=L[1], gy=L[2], gw=L[3], gh=L[4];
    bool in_box = (cx > gx - 0.5f*gw) && (cx < gx + 0.5f*gw) &&
                  (cy > gy - 0.5f*gh) && (cy < gy + 0.5f*gh);
    float rs = 2.5f * ai.s;
    bool in_ctr = (fabsf(cx-gx) < rs) && (fabsf(cy-gy) < rs);
    if (in_box || in_ctr) { anyfg = true; break; }
  }
  float ss = 0.0f;
  if (anyfg) {
    const float* q = base + (size_t)5*ai.hw;
    for (int c = 0; c < NC_; c++) {
      float sc = sigmoidf_(q[(size_t)c*ai.hw]);
      float p = sqrtf(sc * so);
      p = fminf(fmaxf(p, 1e-7f), (float)(1.0 - 1e-6));
      ss += log1pf(-p);
    }
  }
  int idx = b*A_ + a;
  boxw[idx] = bx; sobjw[idx] = so; ssumw[idx] = ss; objlw[idx] = v4;
  fgw[idx] = anyfg ? 1.0f : 0.0f;
}

__global__ __launch_bounds__(256)
void kB_thresh(const float* __restrict__ o0, const float* __restrict__ o1,
               const float* __restrict__ o2, const float* __restrict__ labels,
               const float4* __restrict__ boxw, const float* __restrict__ sobjw,
               const float* __restrict__ ssumw, const float* __restrict__ fgw,
               float* __restrict__ thrw)
{
  int g = blockIdx.x, b = blockIdx.y;
  int tid = threadIdx.x;
  const float* L = labels + (size_t)(b*G_ + g)*5;
  float l0=L[0], gx=L[1], gy=L[2], gw=L[3], gh=L[4];
  bool gvalid = (l0+gx+gy+gw+gh) > 0.0f;
  if (!gvalid) { if (tid==0) thrw[b*G_+g] = -1e30f; return; }
  int gcls = (int)l0;
  float ti[10], tc[10];
  #pragma unroll
  for (int j=0;j<10;j++){ ti[j]=0.0f; tc[j]=3e38f; }
  for (int a = tid; a < A_; a += 256) {
    int idx = b*A_ + a;
    if (fgw[idx] == 0.0f) continue;   // non-candidate: iou_m=0 (covered by init), cost >= 1e9 never in top-k
    AInfo ai = anchor_info(a);
    const float* base = (ai.lvl==0) ? o0 : (ai.lvl==1 ? o1 : o2);
    const float* clsq = base + (size_t)(b*85 + 5)*ai.hw + ai.within;
    float cx = ((float)ai.x + 0.5f)*ai.s, cy = ((float)ai.y + 0.5f)*ai.s;
    float2 ci = cost_iou_fn(gx,gy,gw,gh,gcls, cx,cy,ai.s,
                            boxw[idx], ssumw[idx], sobjw[idx], clsq, ai.hw);
    float v = ci.y;               // iou_m (cand => iou)
    if (v > ti[9]) {
      #pragma unroll
      for (int j=0;j<10;j++){ float o=ti[j]; bool t=v>o; ti[j]=t?v:o; v=t?o:v; }
    }
    float c = ci.x;
    if (c < tc[9]) {
      #pragma unroll
      for (int j=0;j<10;j++){ float o=tc[j]; bool t=c<o; tc[j]=t?c:o; c=t?o:c; }
    }
  }
  __shared__ float sh[256*10];
  __shared__ int s_dk;
  // merge top-10 IoU (descending)
  #pragma unroll
  for (int j=0;j<10;j++) sh[tid*10+j] = ti[j];
  __syncthreads();
  for (int str=128; str>0; str>>=1) {
    if (tid < str) {
      float out[10]; int i=0, jj=0;
      float* Aa = &sh[tid*10]; float* Bb = &sh[(tid+str)*10];
      #pragma unroll
      for (int k=0;k<10;k++){ float va=Aa[i], vb=Bb[jj]; bool t=(va>=vb); out[k]=t?va:vb; if(t)i++; else jj++; }
      #pragma unroll
      for (int k=0;k<10;k++) Aa[k]=out[k];
    }
    __syncthreads();
  }
  if (tid==0) {
    float s10=0.0f;
    #pragma unroll
    for (int j=0;j<10;j++) s10 += sh[j];
    int dk = (int)s10; if (dk<1) dk=1; if (dk>10) dk=10;
    s_dk = dk;
  }
  __syncthreads();
  // merge top-10 smallest cost (ascending)
  #pragma unroll
  for (int j=0;j<10;j++) sh[tid*10+j] = tc[j];
  __syncthreads();
  for (int str=128; str>0; str>>=1) {
    if (tid < str) {
      float out[10]; int i=0, jj=0;
      float* Aa = &sh[tid*10]; float* Bb = &sh[(tid+str)*10];
      #pragma unroll
      for (int k=0;k<10;k++){ float va=Aa[i], vb=Bb[jj]; bool t=(va<=vb); out[k]=t?va:vb; if(t)i++; else jj++; }
      #pragma unroll
      for (int k=0;k<10;k++) Aa[k]=out[k];
    }
    __syncthreads();
  }
  if (tid==0) thrw[b*G_+g] = sh[s_dk-1];
}

__global__ __launch_bounds__(256)
void kC_match(const float* __restrict__ o0, const float* __restrict__ o1,
              const float* __restrict__ o2, const float* __restrict__ labels,
              const float4* __restrict__ boxw, const float* __restrict__ sobjw,
              const float* __restrict__ ssumw, const float* __restrict__ fgw,
              const float* __restrict__ thrw,
              float* __restrict__ fgfw, int* __restrict__ mgtw, float* __restrict__ piouw)
{
  __shared__ float lab[G_*5];
  __shared__ float thrL[G_];
  int b = blockIdx.y;
  for (int i = threadIdx.x; i < G_*5; i += 256) lab[i] = labels[b*G_*5+i];
  if (threadIdx.x < G_) thrL[threadIdx.x] = thrw[b*G_+threadIdx.x];
  __syncthreads();
  int a = blockIdx.x*256 + threadIdx.x;
  if (a >= A_) return;
  int idx = b*A_ + a;
  if (fgw[idx] == 0.0f) { fgfw[idx]=0.0f; mgtw[idx]=0; piouw[idx]=0.0f; return; }
  float4 bx = boxw[idx]; float so = sobjw[idx], ss = ssumw[idx];
  AInfo ai = anchor_info(a);
  const float* base = (ai.lvl==0)? o0 : (ai.lvl==1? o1 : o2);
  const float* clsq = base + (size_t)(b*85+5)*ai.hw + ai.within;
  float cx = ((float)ai.x+0.5f)*ai.s, cy = ((float)ai.y+0.5f)*ai.s;
  float minc = 3e38f; int ming = 0; float miniou = 0.0f;
  int cnt = 0; int firstg = -1; float firstiou = 0.0f;
  for (int g = 0; g < G_; g++) {
    const float* L = &lab[g*5];
    float l0=L[0], gx=L[1], gy=L[2], gw=L[3], gh=L[4];
    if (!((l0+gx+gy+gw+gh) > 0.0f)) continue;   // invalid gt: cost >= 1e9, never argmin for fg anchor, cand false
    float2 ci = cost_iou_fn(gx,gy,gw,gh,(int)l0, cx,cy,ai.s, bx, ss, so, clsq, ai.hw);
    if (ci.x < minc) { minc=ci.x; ming=g; miniou=ci.y; }
    if (ci.x <= thrL[g]) { cnt++; if (firstg<0){firstg=g; firstiou=ci.y;} }
  }
  float fgf; int mg; float pi;
  if (cnt == 0)      { fgf=0.0f; mg=0; pi=0.0f; }
  else if (cnt == 1) { fgf=1.0f; mg=firstg; pi=firstiou; }
  else {
    bool m0bg = (minc <= thrL[ming]);       // keep only best_gt; it may itself be unmatched
    fgf = m0bg?1.0f:0.0f; mg = m0bg?ming:0; pi = m0bg?miniou:0.0f;
  }
  fgfw[idx]=fgf; mgtw[idx]=mg; piouw[idx]=pi;
}

__global__ __launch_bounds__(256)
void kD_loss(const float* __restrict__ o0, const float* __restrict__ o1,
             const float* __restrict__ o2, const float* __restrict__ labels,
             const float4* __restrict__ boxw, const float* __restrict__ objlw,
             const float* __restrict__ fgfw, const int* __restrict__ mgtw,
             const float* __restrict__ piouw, float* __restrict__ acc)
{
  __shared__ float lab[G_*5];
  int b = blockIdx.y;
  for (int i=threadIdx.x;i<G_*5;i+=256) lab[i]=labels[b*G_*5+i];
  __syncthreads();
  int a = blockIdx.x*256 + threadIdx.x;
  float pf=0.0f, pl_iou=0.0f, pl_obj=0.0f, pl_cls=0.0f;
  if (a < A_) {
    int idx = b*A_+a;
    float fgf = fgfw[idx];
    float obj = objlw[idx];
    pl_obj = fmaxf(obj,0.0f) - obj*fgf + log1pf(expf(-fabsf(obj)));
    pf = fgf;
    if (fgf != 0.0f) {
      int mg = mgtw[idx]; float pi = piouw[idx];
      float4 p = boxw[idx];
      float tx=lab[mg*5+1], ty=lab[mg*5+2], tw=lab[mg*5+3], th=lab[mg*5+4];
      float tlx = fmaxf(p.x-p.z*0.5f, tx-tw*0.5f);
      float tly = fmaxf(p.y-p.w*0.5f, ty-th*0.5f);
      float brx = fminf(p.x+p.z*0.5f, tx+tw*0.5f);
      float bry = fminf(p.y+p.w*0.5f, ty+th*0.5f);
      float iw = fmaxf(brx-tlx,0.0f), ih = fmaxf(bry-tly,0.0f);
      float inter = iw*ih;
      float uni = p.z*p.w + tw*th - inter + 1e-16f;
      float iou = inter/uni;
      pl_iou = 1.0f - iou*iou;
      int mcls = (int)lab[mg*5+0];
      AInfo ai = anchor_info(a);
      const float* base = (ai.lvl==0)?o0:(ai.lvl==1?o1:o2);
      const float* clsq = base + (size_t)(b*85+5)*ai.hw + ai.within;
      for (int c=0;c<NC_;c++){
        float x = clsq[(size_t)c*ai.hw];
        float yv = (c==mcls)? pi : 0.0f;
        pl_cls += fmaxf(x,0.0f) - x*yv + log1pf(expf(-fabsf(x)));
      }
    }
  }
  __shared__ float red[256];
  float vals[4] = {pf, pl_iou, pl_obj, pl_cls};
  for (int k=0;k<4;k++){
    red[threadIdx.x] = vals[k];
    __syncthreads();
    for (int s=128;s>0;s>>=1){ if (threadIdx.x<s) red[threadIdx.x]+=red[threadIdx.x+s]; __syncthreads(); }
    if (threadIdx.x==0) atomicAdd(&acc[k], red[0]);
    __syncthreads();
  }
}

__global__ void kE_final(const float* __restrict__ acc, float* __restrict__ out) {
  float nf = fmaxf(acc[0], 1.0f);
  out[0] = 5.0f*(acc[1]/nf) + acc[2]/nf + acc[3]/nf;
}

extern "C" void kernel_launch(void* const* d_in, const int* in_sizes, int n_in,
                              void* d_out, int out_size, void* d_ws, size_t ws_size,
                              hipStream_t stream)
{
  const float* o0 = (const float*)d_in[0];
  const float* o1 = (const float*)d_in[1];
  const float* o2 = (const float*)d_in[2];
  const float* labels = (const float*)d_in[3];
  char* w = (char*)d_ws;
  size_t off = 0;
  auto alloc = [&](size_t bytes) -> void* {
    void* p = w + off; off += (bytes + 255) & ~(size_t)255; return p;
  };
  float4* boxw = (float4*)alloc(sizeof(float4)*(size_t)B_*A_);
  float*  sobjw= (float*) alloc(sizeof(float)*(size_t)B_*A_);
  float*  ssumw= (float*) alloc(sizeof(float)*(size_t)B_*A_);
  float*  objlw= (float*) alloc(sizeof(float)*(size_t)B_*A_);
  float*  fgw  = (float*) alloc(sizeof(float)*(size_t)B_*A_);
  float*  thrw = (float*) alloc(sizeof(float)*(size_t)B_*G_);
  float*  fgfw = (float*) alloc(sizeof(float)*(size_t)B_*A_);
  int*    mgtw = (int*)   alloc(sizeof(int)*(size_t)B_*A_);
  float*  piouw= (float*) alloc(sizeof(float)*(size_t)B_*A_);
  float*  acc  = (float*) alloc(sizeof(float)*4);

  hipMemsetAsync(acc, 0, sizeof(float)*4, stream);
  dim3 grdA((A_+255)/256, B_);
  kA_decode<<<grdA, 256, 0, stream>>>(o0,o1,o2,labels,boxw,sobjw,ssumw,objlw,fgw);
  kB_thresh<<<dim3(G_,B_), 256, 0, stream>>>(o0,o1,o2,labels,boxw,sobjw,ssumw,fgw,thrw);
  kC_match<<<grdA, 256, 0, stream>>>(o0,o1,o2,labels,boxw,sobjw,ssumw,fgw,thrw,fgfw,mgtw,piouw);
  kD_loss<<<grdA, 256, 0, stream>>>(o0,o1,o2,labels,boxw,objlw,fgfw,mgtw,piouw,acc);
  kE_final<<<1,1,0,stream>>>(acc, (float*)d_out);
}

// Round 2
// 254.487 us; speedup vs baseline: 1.8951x; 1.8951x over previous
//
#include <hip/hip_runtime.h>
#include <math.h>

#define B_  32
#define A_  8400
#define G_  50
#define NC_ 80
#define CLIPHI ((float)(1.0 - 1e-6))

#define ACC_NUMFG 0
#define ACC_IOU   1
#define ACC_OBJ0  2   // sum over ALL anchors of bce(obj,0)
#define ACC_OBJFG 3   // sum over matched anchors of obj logit (subtracted in kE)
#define ACC_CLS   4

struct AInfo { int lvl; int within; int w; int hw; float s; int x; int y; };

__device__ __forceinline__ AInfo anchor_info(int a) {
  AInfo r;
  if (a < 6400)      { r.lvl = 0; r.within = a;        r.w = 80; r.hw = 6400; r.s = 8.0f;  }
  else if (a < 8000) { r.lvl = 1; r.within = a - 6400; r.w = 40; r.hw = 1600; r.s = 16.0f; }
  else               { r.lvl = 2; r.within = a - 8000; r.w = 20; r.hw = 400;  r.s = 32.0f; }
  r.x = r.within % r.w; r.y = r.within / r.w;
  return r;
}

__device__ __forceinline__ const float* lvl_base(const float* o0, const float* o1,
                                                 const float* o2, int lvl) {
  return lvl == 0 ? o0 : (lvl == 1 ? o1 : o2);
}

// Shared cost function. __noinline__ -> emitted once, so kB and kC see
// bitwise-identical cost values (the cost <= thr comparisons must agree).
// Center coords computed INSIDE so both callers share the same rounding.
__device__ __attribute__((noinline)) float2 cost_iou_fn(
    float gx, float gy, float gw, float gh,
    float fx, float fy, float st,
    float4 bx, float ssum, float sobj, float clsv)
{
  float cx = (fx + 0.5f) * st;
  float cy = (fy + 0.5f) * st;
  bool in_box = (cx > gx - 0.5f*gw) && (cx < gx + 0.5f*gw) &&
                (cy > gy - 0.5f*gh) && (cy < gy + 0.5f*gh);
  float rs = 2.5f * st;
  bool in_ctr = (fabsf(cx - gx) < rs) && (fabsf(cy - gy) < rs);
  bool geom = in_box && in_ctr;
  float tlx = fmaxf(gx - gw*0.5f, bx.x - bx.z*0.5f);
  float tly = fmaxf(gy - gh*0.5f, bx.y - bx.w*0.5f);
  float brx = fminf(gx + gw*0.5f, bx.x + bx.z*0.5f);
  float bry = fminf(gy + gh*0.5f, bx.y + bx.w*0.5f);
  bool en = (tlx < brx) && (tly < bry);
  float inter = en ? (brx - tlx) * (bry - tly) : 0.0f;
  float iou = inter / (gw*gh + bx.z*bx.w - inter + 1e-12f);
  float iou_cost = -__logf(iou + 1e-8f);
  float sc = 1.0f / (1.0f + __expf(-clsv));
  float p = sqrtf(sc * sobj);
  p = fminf(fmaxf(p, 1e-7f), CLIPHI);
  float cls_cost = -__logf(p) + __logf(1.0f - p) - ssum;
  float cost = cls_cost + 3.0f * iou_cost;
  if (!geom) cost += 100000.0f;
  return make_float2(cost, iou);
}

// kA: decode, obj bce(x,0) over all anchors, candidate (fg) detection + ssum,
// wave-aggregated compaction of candidates.
__global__ __launch_bounds__(256)
void kA_decode(const float* __restrict__ o0, const float* __restrict__ o1,
               const float* __restrict__ o2, const float* __restrict__ labels,
               float4* __restrict__ cBox, float4* __restrict__ cMeta,
               int* __restrict__ ncand, float* __restrict__ acc)
{
  __shared__ float lab[G_*5];
  __shared__ float wsum[4];
  int b = blockIdx.y;
  for (int i = threadIdx.x; i < G_*5; i += 256) lab[i] = labels[b*G_*5 + i];
  __syncthreads();
  int a = blockIdx.x*256 + threadIdx.x;
  float objbce = 0.0f;
  bool anyfg = false;
  float4 bx = make_float4(0.f,0.f,0.f,0.f);
  float v4 = 0.0f, so = 0.0f, ss = 0.0f;
  if (a < A_) {
    AInfo ai = anchor_info(a);
    const float* base = lvl_base(o0,o1,o2,ai.lvl) + (size_t)b*85*ai.hw + ai.within;
    float v0 = base[0];
    float v1 = base[(size_t)1*ai.hw];
    float v2 = base[(size_t)2*ai.hw];
    float v3 = base[(size_t)3*ai.hw];
    v4 = base[(size_t)4*ai.hw];
    bx.x = (v0 + (float)ai.x) * ai.s;
    bx.y = (v1 + (float)ai.y) * ai.s;
    bx.z = __expf(v2) * ai.s;
    bx.w = __expf(v3) * ai.s;
    objbce = fmaxf(v4, 0.0f) + __logf(1.0f + __expf(-fabsf(v4)));
    float cx = ((float)ai.x + 0.5f) * ai.s;
    float cy = ((float)ai.y + 0.5f) * ai.s;
    float rs = 2.5f * ai.s;
    for (int g = 0; g < G_; g++) {
      const float* L = &lab[g*5];
      float l0=L[0], gx=L[1], gy=L[2], gw=L[3], gh=L[4];
      if (!((l0+gx+gy+gw+gh) > 0.0f)) continue;
      bool in_box = (cx > gx-0.5f*gw) && (cx < gx+0.5f*gw) &&
                    (cy > gy-0.5f*gh) && (cy < gy+0.5f*gh);
      bool in_ctr = (fabsf(cx-gx) < rs) && (fabsf(cy-gy) < rs);
      if (in_box || in_ctr) { anyfg = true; break; }
    }
    if (anyfg) {
      so = 1.0f / (1.0f + __expf(-v4));
      const float* q = base + (size_t)5*ai.hw;
      #pragma unroll 4
      for (int c = 0; c < NC_; c++) {
        float sc = 1.0f / (1.0f + __expf(-q[(size_t)c*ai.hw]));
        float p = sqrtf(sc * so);
        p = fminf(fmaxf(p, 1e-7f), CLIPHI);
        ss += __logf(1.0f - p);
      }
    }
  }
  // block-reduce obj bce -> 1 atomic per block
  float v = objbce;
  for (int o = 32; o > 0; o >>= 1) v += __shfl_down(v, o, 64);
  if ((threadIdx.x & 63) == 0) wsum[threadIdx.x >> 6] = v;
  __syncthreads();
  if (threadIdx.x == 0) atomicAdd(&acc[ACC_OBJ0], wsum[0]+wsum[1]+wsum[2]+wsum[3]);
  // candidate compaction (compiler wave-aggregates same-address atomicAdd)
  if (anyfg) {
    int pos = atomicAdd(&ncand[b], 1);
    cBox[b*A_ + pos] = bx;
    cMeta[b*A_ + pos] = make_float4(ss, so, v4, __int_as_float(a));
  }
}

// kB: per (gt,image) dynamic-k threshold over the compacted candidate list.
__global__ __launch_bounds__(256)
void kB_thresh(const float* __restrict__ o0, const float* __restrict__ o1,
               const float* __restrict__ o2, const float* __restrict__ labels,
               const float4* __restrict__ cBox, const float4* __restrict__ cMeta,
               const int* __restrict__ ncand, float* __restrict__ thrw)
{
  __shared__ float sh[256*10];
  __shared__ int s_dk;
  int g = blockIdx.x, b = blockIdx.y;
  int tid = threadIdx.x;
  const float* L = labels + (size_t)(b*G_ + g)*5;
  float l0=L[0], gx=L[1], gy=L[2], gw=L[3], gh=L[4];
  bool gvalid = (l0+gx+gy+gw+gh) > 0.0f;
  if (!gvalid) { if (tid==0) thrw[b*G_+g] = -3.0e38f; return; }
  int gcls = (int)l0;
  int nc = ncand[b];
  float ti[10], tc[10];
  #pragma unroll
  for (int j=0;j<10;j++){ ti[j]=0.0f; tc[j]=3e38f; }
  for (int i = tid; i < nc; i += 256) {
    float4 bx = cBox[b*A_ + i];
    float4 mt = cMeta[b*A_ + i];
    int a = __float_as_int(mt.w);
    AInfo ai = anchor_info(a);
    const float* basep = lvl_base(o0,o1,o2,ai.lvl);
    float clsv = basep[(size_t)(b*85 + 5 + gcls)*ai.hw + ai.within];
    float2 ci = cost_iou_fn(gx,gy,gw,gh,(float)ai.x,(float)ai.y,ai.s,
                            bx, mt.x, mt.y, clsv);
    float v = ci.y;
    if (v > ti[9]) {
      #pragma unroll
      for (int j=0;j<10;j++){ float o=ti[j]; bool t=v>o; ti[j]=t?v:o; v=t?o:v; }
    }
    float c = ci.x;
    if (c < tc[9]) {
      #pragma unroll
      for (int j=0;j<10;j++){ float o=tc[j]; bool t=c<o; tc[j]=t?c:o; c=t?o:c; }
    }
  }
  // merge top-10 IoU (descending)
  #pragma unroll
  for (int j=0;j<10;j++) sh[tid*10+j] = ti[j];
  __syncthreads();
  for (int str=128; str>0; str>>=1) {
    if (tid < str) {
      float out[10]; int i=0, jj=0;
      float* Aa = &sh[tid*10]; float* Bb = &sh[(tid+str)*10];
      #pragma unroll
      for (int k=0;k<10;k++){ float va=Aa[i], vb=Bb[jj]; bool t=(va>=vb); out[k]=t?va:vb; if(t)i++; else jj++; }
      #pragma unroll
      for (int k=0;k<10;k++) Aa[k]=out[k];
    }
    __syncthreads();
  }
  if (tid==0) {
    float s10=0.0f;
    #pragma unroll
    for (int j=0;j<10;j++) s10 += sh[j];
    int dk = (int)s10; if (dk<1) dk=1; if (dk>10) dk=10;
    s_dk = dk;
  }
  __syncthreads();
  // merge top-10 smallest cost (ascending)
  #pragma unroll
  for (int j=0;j<10;j++) sh[tid*10+j] = tc[j];
  __syncthreads();
  for (int str=128; str>0; str>>=1) {
    if (tid < str) {
      float out[10]; int i=0, jj=0;
      float* Aa = &sh[tid*10]; float* Bb = &sh[(tid+str)*10];
      #pragma unroll
      for (int k=0;k<10;k++){ float va=Aa[i], vb=Bb[jj]; bool t=(va<=vb); out[k]=t?va:vb; if(t)i++; else jj++; }
      #pragma unroll
      for (int k=0;k<10;k++) Aa[k]=out[k];
    }
    __syncthreads();
  }
  if (tid==0) thrw[b*G_+g] = sh[s_dk-1];
}

// kC: one WAVE per candidate (lane g handles gt g); matching via packed-key
// argmin + ballot; losses (iou/obj-fg/cls over 80 classes spread on lanes)
// accumulated per wave, 4 atomics per block.
__global__ __launch_bounds__(256)
void kC_loss(const float* __restrict__ o0, const float* __restrict__ o1,
             const float* __restrict__ o2, const float* __restrict__ labels,
             const float4* __restrict__ cBox, const float4* __restrict__ cMeta,
             const int* __restrict__ ncand, const float* __restrict__ thrw,
             float* __restrict__ acc)
{
  int b = blockIdx.y;
  int nc = ncand[b];
  if (nc <= 0) return;
  __shared__ float lab[G_*5];
  __shared__ float wpart[4][4];
  for (int i = threadIdx.x; i < G_*5; i += 256) lab[i] = labels[b*G_*5 + i];
  __syncthreads();
  int lane = threadIdx.x & 63;
  int w = threadIdx.x >> 6;
  float thr_g = (lane < G_) ? thrw[b*G_ + lane] : -3.0e38f;
  float gl0=0.f, ggx=0.f, ggy=0.f, ggw=0.f, ggh=0.f; bool gval=false;
  if (lane < G_) {
    gl0 = lab[lane*5+0]; ggx = lab[lane*5+1]; ggy = lab[lane*5+2];
    ggw = lab[lane*5+3]; ggh = lab[lane*5+4];
    gval = (gl0+ggx+ggy+ggw+ggh) > 0.0f;
  }
  int gcls_l = (int)gl0;
  float accPf=0.f, accIou=0.f, accObjx=0.f, accCls=0.f;
  for (int i = blockIdx.x*4 + w; i < nc; i += 132) {
    float4 bx = cBox[b*A_ + i];
    float4 mt = cMeta[b*A_ + i];
    int a = __float_as_int(mt.w);
    AInfo ai = anchor_info(a);
    const float* clsbase = lvl_base(o0,o1,o2,ai.lvl) + (size_t)(b*85 + 5)*ai.hw + ai.within;
    float cost = __uint_as_float(0x7f800000u);   // +inf
    float iou = 0.0f;
    if (gval) {
      float clsv = clsbase[(size_t)gcls_l * ai.hw];
      float2 ci = cost_iou_fn(ggx,ggy,ggw,ggh,(float)ai.x,(float)ai.y,ai.s,
                              bx, mt.x, mt.y, clsv);
      cost = ci.x; iou = ci.y;
    }
    // wave argmin over (cost, g); cost > 0 so uint bits are order-preserving.
    unsigned long long key = ((unsigned long long)__float_as_uint(cost) << 32) | (unsigned)lane;
    #pragma unroll
    for (int o = 1; o < 64; o <<= 1) {
      unsigned long long other = __shfl_xor(key, o, 64);
      key = (other < key) ? other : key;
    }
    int ming = (int)(key & 0xffffffffull);
    float minc = __uint_as_float((unsigned)(key >> 32));
    bool matched = gval && (cost <= thr_g);
    unsigned long long mm = __ballot(matched);
    int cnt = __popcll(mm);
    float fgf = 0.0f; int mg = 0; float pi = 0.0f;
    if (cnt == 1) {
      mg = __ffsll((unsigned long long)mm) - 1;
      pi = __shfl(iou, mg, 64);
      fgf = 1.0f;
    } else if (cnt > 1) {
      float thr_m = __shfl(thr_g, ming, 64);
      if (minc <= thr_m) { fgf = 1.0f; mg = ming; pi = __shfl(iou, ming, 64); }
    }
    if (fgf != 0.0f) {
      int mcls = (int)lab[mg*5+0];
      float x1 = clsbase[(size_t)lane * ai.hw];
      accCls += fmaxf(x1,0.0f) - x1*((lane==mcls)?pi:0.0f) + __logf(1.0f + __expf(-fabsf(x1)));
      if (lane < NC_ - 64) {
        int c2 = lane + 64;
        float x2 = clsbase[(size_t)c2 * ai.hw];
        accCls += fmaxf(x2,0.0f) - x2*((c2==mcls)?pi:0.0f) + __logf(1.0f + __expf(-fabsf(x2)));
      }
      if (lane == 0) {
        accPf += 1.0f;
        accObjx += mt.z;
        float tx=lab[mg*5+1], ty=lab[mg*5+2], tw=lab[mg*5+3], th=lab[mg*5+4];
        float tlx = fmaxf(bx.x - bx.z*0.5f, tx - tw*0.5f);
        float tly = fmaxf(bx.y - bx.w*0.5f, ty - th*0.5f);
        float brx = fminf(bx.x + bx.z*0.5f, tx + tw*0.5f);
        float bry = fminf(bx.y + bx.w*0.5f, ty + th*0.5f);
        float iw = fmaxf(brx-tlx, 0.0f), ih = fmaxf(bry-tly, 0.0f);
        float inter = iw*ih;
        float uni = bx.z*bx.w + tw*th - inter + 1e-16f;
        float iou2 = inter/uni;
        accIou += 1.0f - iou2*iou2;
      }
    }
  }
  for (int o = 32; o > 0; o >>= 1) {
    accPf   += __shfl_down(accPf,   o, 64);
    accIou  += __shfl_down(accIou,  o, 64);
    accObjx += __shfl_down(accObjx, o, 64);
    accCls  += __shfl_down(accCls,  o, 64);
  }
  if (lane == 0) { wpart[w][0]=accPf; wpart[w][1]=accIou; wpart[w][2]=accObjx; wpart[w][3]=accCls; }
  __syncthreads();
  if (threadIdx.x == 0) {
    float s0=0.f,s1=0.f,s2=0.f,s3=0.f;
    for (int q=0;q<4;q++){ s0+=wpart[q][0]; s1+=wpart[q][1]; s2+=wpart[q][2]; s3+=wpart[q][3]; }
    if (s0!=0.f) atomicAdd(&acc[ACC_NUMFG], s0);
    if (s1!=0.f) atomicAdd(&acc[ACC_IOU],   s1);
    if (s2!=0.f) atomicAdd(&acc[ACC_OBJFG], s2);
    if (s3!=0.f) atomicAdd(&acc[ACC_CLS],   s3);
  }
}

__global__ void kE_final(const float* __restrict__ acc, float* __restrict__ out) {
  float nf = fmaxf(acc[ACC_NUMFG], 1.0f);
  out[0] = (5.0f*acc[ACC_IOU] + (acc[ACC_OBJ0] - acc[ACC_OBJFG]) + acc[ACC_CLS]) / nf;
}

extern "C" void kernel_launch(void* const* d_in, const int* in_sizes, int n_in,
                              void* d_out, int out_size, void* d_ws, size_t ws_size,
                              hipStream_t stream)
{
  const float* o0 = (const float*)d_in[0];
  const float* o1 = (const float*)d_in[1];
  const float* o2 = (const float*)d_in[2];
  const float* labels = (const float*)d_in[3];
  char* w = (char*)d_ws;
  size_t off = 0;
  auto alloc = [&](size_t bytes) -> void* {
    void* p = w + off; off += (bytes + 255) & ~(size_t)255; return p;
  };
  float4* cBox  = (float4*)alloc(sizeof(float4)*(size_t)B_*A_);
  float4* cMeta = (float4*)alloc(sizeof(float4)*(size_t)B_*A_);
  float*  thrw  = (float*) alloc(sizeof(float)*(size_t)B_*G_);
  int*    ncand = (int*)   alloc(sizeof(int)*B_);
  float*  acc   = (float*) alloc(sizeof(float)*8);

  hipMemsetAsync(ncand, 0, sizeof(int)*B_, stream);
  hipMemsetAsync(acc, 0, sizeof(float)*8, stream);

  dim3 grdA((A_+255)/256, B_);
  kA_decode<<<grdA, 256, 0, stream>>>(o0,o1,o2,labels,cBox,cMeta,ncand,acc);
  kB_thresh<<<dim3(G_,B_), 256, 0, stream>>>(o0,o1,o2,labels,cBox,cMeta,ncand,thrw);
  kC_loss<<<grdA, 256, 0, stream>>>(o0,o1,o2,labels,cBox,cMeta,ncand,thrw,acc);
  kE_final<<<1,1,0,stream>>>(acc, (float*)d_out);
}

// Round 3
// 246.504 us; speedup vs baseline: 1.9565x; 1.0324x over previous
//
#include <hip/hip_runtime.h>
#include <math.h>

#define B_  32
#define A_  8400
#define G_  50
#define NC_ 80
#define CLIPHI ((float)(1.0 - 1e-6))

#define ACC_NUMFG 0
#define ACC_IOU   1
#define ACC_OBJ0  2   // sum over ALL anchors of bce(obj,0)
#define ACC_OBJFG 3   // sum over matched anchors of obj logit (subtracted in kE)
#define ACC_CLS   4

struct AInfo { int lvl; int within; int w; int hw; float s; int x; int y; };

__device__ __forceinline__ AInfo anchor_info(int a) {
  AInfo r;
  if (a < 6400)      { r.lvl = 0; r.within = a;        r.w = 80; r.hw = 6400; r.s = 8.0f;  }
  else if (a < 8000) { r.lvl = 1; r.within = a - 6400; r.w = 40; r.hw = 1600; r.s = 16.0f; }
  else               { r.lvl = 2; r.within = a - 8000; r.w = 20; r.hw = 400;  r.s = 32.0f; }
  r.x = r.within % r.w; r.y = r.within / r.w;
  return r;
}

__device__ __forceinline__ const float* lvl_base(const float* o0, const float* o1,
                                                 const float* o2, int lvl) {
  return lvl == 0 ? o0 : (lvl == 1 ? o1 : o2);
}

// Shared cost function. __noinline__ -> emitted once, so kB and kC see
// bitwise-identical cost values (the cost <= thr comparisons must agree).
__device__ __attribute__((noinline)) float2 cost_iou_fn(
    float gx, float gy, float gw, float gh,
    float fx, float fy, float st,
    float4 bx, float ssum, float sobj, float clsv)
{
  float cx = (fx + 0.5f) * st;
  float cy = (fy + 0.5f) * st;
  bool in_box = (cx > gx - 0.5f*gw) && (cx < gx + 0.5f*gw) &&
                (cy > gy - 0.5f*gh) && (cy < gy + 0.5f*gh);
  float rs = 2.5f * st;
  bool in_ctr = (fabsf(cx - gx) < rs) && (fabsf(cy - gy) < rs);
  bool geom = in_box && in_ctr;
  float tlx = fmaxf(gx - gw*0.5f, bx.x - bx.z*0.5f);
  float tly = fmaxf(gy - gh*0.5f, bx.y - bx.w*0.5f);
  float brx = fminf(gx + gw*0.5f, bx.x + bx.z*0.5f);
  float bry = fminf(gy + gh*0.5f, bx.y + bx.w*0.5f);
  bool en = (tlx < brx) && (tly < bry);
  float inter = en ? (brx - tlx) * (bry - tly) : 0.0f;
  float iou = inter / (gw*gh + bx.z*bx.w - inter + 1e-12f);
  float iou_cost = -__logf(iou + 1e-8f);
  float sc = 1.0f / (1.0f + __expf(-clsv));
  float p = sqrtf(sc * sobj);
  p = fminf(fmaxf(p, 1e-7f), CLIPHI);
  float cls_cost = -__logf(p) + __logf(1.0f - p) - ssum;
  float cost = cls_cost + 3.0f * iou_cost;
  if (!geom) cost += 100000.0f;
  return make_float2(cost, iou);
}

// kA: decode, obj bce(x,0) over all anchors, candidate (fg) detection via
// precomputed per-GT bounds in LDS, wave-aggregated compaction.
__global__ __launch_bounds__(256)
void kA_decode(const float* __restrict__ o0, const float* __restrict__ o1,
               const float* __restrict__ o2, const float* __restrict__ labels,
               float4* __restrict__ cBox, float4* __restrict__ cMeta,
               int* __restrict__ ncand, float* __restrict__ acc)
{
  __shared__ float gl[G_], gr[G_], gtt[G_], gbb[G_], gcx[G_], gcy[G_];
  __shared__ int vflag[G_];
  __shared__ int nvgS;
  __shared__ float wsum[4];
  int b = blockIdx.y;
  int tid = threadIdx.x;
  if (tid < G_) {
    const float* L = labels + (size_t)b*G_*5 + tid*5;
    float l0=L[0], gx=L[1], gy=L[2], gw=L[3], gh=L[4];
    vflag[tid] = ((l0+gx+gy+gw+gh) > 0.0f) ? 1 : 0;
    gl[tid] = gx - 0.5f*gw; gr[tid] = gx + 0.5f*gw;
    gtt[tid] = gy - 0.5f*gh; gbb[tid] = gy + 0.5f*gh;
    gcx[tid] = gx; gcy[tid] = gy;
  }
  __syncthreads();
  if (tid == 0) {
    int n = 0;
    for (int g = 0; g < G_; g++) {
      if (vflag[g]) {
        gl[n]=gl[g]; gr[n]=gr[g]; gtt[n]=gtt[g]; gbb[n]=gbb[g];
        gcx[n]=gcx[g]; gcy[n]=gcy[g]; n++;
      }
    }
    nvgS = n;
  }
  __syncthreads();
  int nvg = nvgS;
  int a = blockIdx.x*256 + tid;
  float objbce = 0.0f;
  bool anyfg = false;
  float4 bx = make_float4(0.f,0.f,0.f,0.f);
  float v4 = 0.0f, so = 0.0f;
  if (a < A_) {
    AInfo ai = anchor_info(a);
    const float* base = lvl_base(o0,o1,o2,ai.lvl) + (size_t)b*85*ai.hw + ai.within;
    float v0 = base[0];
    float v1 = base[(size_t)1*ai.hw];
    float v2 = base[(size_t)2*ai.hw];
    float v3 = base[(size_t)3*ai.hw];
    v4 = base[(size_t)4*ai.hw];
    bx.x = (v0 + (float)ai.x) * ai.s;
    bx.y = (v1 + (float)ai.y) * ai.s;
    bx.z = __expf(v2) * ai.s;
    bx.w = __expf(v3) * ai.s;
    objbce = fmaxf(v4, 0.0f) + __logf(1.0f + __expf(-fabsf(v4)));
    float cx = ((float)ai.x + 0.5f) * ai.s;
    float cy = ((float)ai.y + 0.5f) * ai.s;
    float rs = 2.5f * ai.s;
    for (int k = 0; k < nvg; k++) {
      bool in_box = (cx > gl[k]) && (cx < gr[k]) && (cy > gtt[k]) && (cy < gbb[k]);
      bool in_ctr = (fabsf(cx - gcx[k]) < rs) && (fabsf(cy - gcy[k]) < rs);
      if (in_box || in_ctr) { anyfg = true; break; }
    }
    if (anyfg) so = 1.0f / (1.0f + __expf(-v4));
  }
  // block-reduce obj bce -> 1 atomic per block
  float v = objbce;
  for (int o = 32; o > 0; o >>= 1) v += __shfl_down(v, o, 64);
  if ((tid & 63) == 0) wsum[tid >> 6] = v;
  __syncthreads();
  if (tid == 0) atomicAdd(&acc[ACC_OBJ0], wsum[0]+wsum[1]+wsum[2]+wsum[3]);
  if (anyfg) {
    int pos = atomicAdd(&ncand[b], 1);
    cBox[b*A_ + pos] = bx;
    cMeta[b*A_ + pos] = make_float4(so, v4, __int_as_float(a), 0.0f);
  }
}

// kS: dense ssum over compacted candidates; repack into cPack.
__global__ __launch_bounds__(256)
void kS_ssum(const float* __restrict__ o0, const float* __restrict__ o1,
             const float* __restrict__ o2, const float4* __restrict__ cMeta,
             const int* __restrict__ ncand, float4* __restrict__ cPack)
{
  int b = blockIdx.y;
  int nc = ncand[b];
  if (blockIdx.x*256 >= nc) return;
  int i = blockIdx.x*256 + threadIdx.x;
  if (i >= nc) return;
  float4 mt = cMeta[b*A_ + i];
  float so = mt.x;
  int a = __float_as_int(mt.z);
  AInfo ai = anchor_info(a);
  const float* q = lvl_base(o0,o1,o2,ai.lvl) + (size_t)(b*85 + 5)*ai.hw + ai.within;
  float s0=0,s1=0,s2=0,s3=0,s4=0,s5=0,s6=0,s7=0;
  for (int c = 0; c < NC_; c += 8) {
    float x0 = q[(size_t)(c+0)*ai.hw];
    float x1 = q[(size_t)(c+1)*ai.hw];
    float x2 = q[(size_t)(c+2)*ai.hw];
    float x3 = q[(size_t)(c+3)*ai.hw];
    float x4 = q[(size_t)(c+4)*ai.hw];
    float x5 = q[(size_t)(c+5)*ai.hw];
    float x6 = q[(size_t)(c+6)*ai.hw];
    float x7 = q[(size_t)(c+7)*ai.hw];
    #define TERM(xx, ss_) { \
      float sc = 1.0f/(1.0f+__expf(-(xx))); \
      float p = sqrtf(sc*so); \
      p = fminf(fmaxf(p,1e-7f), CLIPHI); \
      ss_ += __logf(1.0f - p); }
    TERM(x0,s0) TERM(x1,s1) TERM(x2,s2) TERM(x3,s3)
    TERM(x4,s4) TERM(x5,s5) TERM(x6,s6) TERM(x7,s7)
    #undef TERM
  }
  float ss = ((s0+s1)+(s2+s3)) + ((s4+s5)+(s6+s7));
  cPack[b*A_ + i] = make_float4(ss, so, mt.z, mt.y);  // ss, so, anchor, v4
}

// kB: per (gt,image) dynamic-k threshold over the compacted candidate list.
__global__ __launch_bounds__(256)
void kB_thresh(const float* __restrict__ o0, const float* __restrict__ o1,
               const float* __restrict__ o2, const float* __restrict__ labels,
               const float4* __restrict__ cBox, const float4* __restrict__ cPack,
               const int* __restrict__ ncand, float* __restrict__ thrw)
{
  __shared__ float sh[256*10];
  __shared__ int s_dk;
  int g = blockIdx.x, b = blockIdx.y;
  int tid = threadIdx.x;
  const float* L = labels + (size_t)(b*G_ + g)*5;
  float l0=L[0], gx=L[1], gy=L[2], gw=L[3], gh=L[4];
  bool gvalid = (l0+gx+gy+gw+gh) > 0.0f;
  if (!gvalid) { if (tid==0) thrw[b*G_+g] = -3.0e38f; return; }
  int gcls = (int)l0;
  int nc = ncand[b];
  float ti[10], tc[10];
  #pragma unroll
  for (int j=0;j<10;j++){ ti[j]=0.0f; tc[j]=3e38f; }
  for (int i = tid; i < nc; i += 256) {
    float4 bx = cBox[b*A_ + i];
    float4 pk = cPack[b*A_ + i];
    int a = __float_as_int(pk.z);
    AInfo ai = anchor_info(a);
    const float* basep = lvl_base(o0,o1,o2,ai.lvl);
    float clsv = basep[(size_t)(b*85 + 5 + gcls)*ai.hw + ai.within];
    float2 ci = cost_iou_fn(gx,gy,gw,gh,(float)ai.x,(float)ai.y,ai.s,
                            bx, pk.x, pk.y, clsv);
    float v = ci.y;
    if (v > ti[9]) {
      #pragma unroll
      for (int j=0;j<10;j++){ float o=ti[j]; bool t=v>o; ti[j]=t?v:o; v=t?o:v; }
    }
    float c = ci.x;
    if (c < tc[9]) {
      #pragma unroll
      for (int j=0;j<10;j++){ float o=tc[j]; bool t=c<o; tc[j]=t?c:o; c=t?o:c; }
    }
  }
  // merge top-10 IoU (descending)
  #pragma unroll
  for (int j=0;j<10;j++) sh[tid*10+j] = ti[j];
  __syncthreads();
  for (int str=128; str>0; str>>=1) {
    if (tid < str) {
      float out[10]; int i=0, jj=0;
      float* Aa = &sh[tid*10]; float* Bb = &sh[(tid+str)*10];
      #pragma unroll
      for (int k=0;k<10;k++){ float va=Aa[i], vb=Bb[jj]; bool t=(va>=vb); out[k]=t?va:vb; if(t)i++; else jj++; }
      #pragma unroll
      for (int k=0;k<10;k++) Aa[k]=out[k];
    }
    __syncthreads();
  }
  if (tid==0) {
    float s10=0.0f;
    #pragma unroll
    for (int j=0;j<10;j++) s10 += sh[j];
    int dk = (int)s10; if (dk<1) dk=1; if (dk>10) dk=10;
    s_dk = dk;
  }
  __syncthreads();
  // merge top-10 smallest cost (ascending)
  #pragma unroll
  for (int j=0;j<10;j++) sh[tid*10+j] = tc[j];
  __syncthreads();
  for (int str=128; str>0; str>>=1) {
    if (tid < str) {
      float out[10]; int i=0, jj=0;
      float* Aa = &sh[tid*10]; float* Bb = &sh[(tid+str)*10];
      #pragma unroll
      for (int k=0;k<10;k++){ float va=Aa[i], vb=Bb[jj]; bool t=(va<=vb); out[k]=t?va:vb; if(t)i++; else jj++; }
      #pragma unroll
      for (int k=0;k<10;k++) Aa[k]=out[k];
    }
    __syncthreads();
  }
  if (tid==0) thrw[b*G_+g] = sh[s_dk-1];
}

// kC: thread per candidate; serial loop over compacted valid-GT list;
// match resolution + all fg losses; block-reduce -> 4 atomics.
__global__ __launch_bounds__(256)
void kC_loss(const float* __restrict__ o0, const float* __restrict__ o1,
             const float* __restrict__ o2, const float* __restrict__ labels,
             const float4* __restrict__ cBox, const float4* __restrict__ cPack,
             const int* __restrict__ ncand, const float* __restrict__ thrw,
             float* __restrict__ acc)
{
  int b = blockIdx.y;
  int nc = ncand[b];
  if (blockIdx.x*256 >= nc) return;
  __shared__ float labS[G_*5];
  __shared__ float thrS[G_];
  __shared__ int vgIdx[G_];
  __shared__ int nvgS;
  __shared__ float wpart[4][4];
  int tid = threadIdx.x;
  for (int i = tid; i < G_*5; i += 256) labS[i] = labels[(size_t)b*G_*5 + i];
  if (tid < G_) thrS[tid] = thrw[b*G_ + tid];
  __syncthreads();
  if (tid == 0) {
    int n = 0;
    for (int g = 0; g < G_; g++) {
      float s5 = labS[g*5]+labS[g*5+1]+labS[g*5+2]+labS[g*5+3]+labS[g*5+4];
      if (s5 > 0.0f) vgIdx[n++] = g;
    }
    nvgS = n;
  }
  __syncthreads();
  int nvg = nvgS;
  int i = blockIdx.x*256 + tid;
  float accPf=0.f, accIou=0.f, accObjx=0.f, accCls=0.f;
  if (i < nc) {
    float4 bx = cBox[b*A_ + i];
    float4 pk = cPack[b*A_ + i];
    float ss = pk.x, so = pk.y, v4 = pk.w;
    int a = __float_as_int(pk.z);
    AInfo ai = anchor_info(a);
    const float* clsbase = lvl_base(o0,o1,o2,ai.lvl) + (size_t)(b*85 + 5)*ai.hw + ai.within;
    float minc = 3e38f; int ming = 0; float miniou = 0.0f;
    int cnt = 0; int firstg = -1; float firstiou = 0.0f;
    for (int k = 0; k < nvg; k++) {
      int g = vgIdx[k];
      float gx = labS[g*5+1], gy = labS[g*5+2], gw = labS[g*5+3], gh = labS[g*5+4];
      int gcls = (int)labS[g*5];
      float clsv = clsbase[(size_t)gcls * ai.hw];
      float2 ci = cost_iou_fn(gx,gy,gw,gh,(float)ai.x,(float)ai.y,ai.s,
                              bx, ss, so, clsv);
      if (ci.x < minc) { minc = ci.x; ming = g; miniou = ci.y; }
      if (ci.x <= thrS[g]) { cnt++; if (firstg < 0) { firstg = g; firstiou = ci.y; } }
    }
    float fgf = 0.0f; int mg = 0; float pi = 0.0f;
    if (cnt == 1)      { fgf = 1.0f; mg = firstg; pi = firstiou; }
    else if (cnt > 1)  { if (minc <= thrS[ming]) { fgf = 1.0f; mg = ming; pi = miniou; } }
    if (fgf != 0.0f) {
      accPf = 1.0f;
      accObjx = v4;
      float tx=labS[mg*5+1], ty=labS[mg*5+2], tw=labS[mg*5+3], th=labS[mg*5+4];
      float tlx = fmaxf(bx.x - bx.z*0.5f, tx - tw*0.5f);
      float tly = fmaxf(bx.y - bx.w*0.5f, ty - th*0.5f);
      float brx = fminf(bx.x + bx.z*0.5f, tx + tw*0.5f);
      float bry = fminf(bx.y + bx.w*0.5f, ty + th*0.5f);
      float iw = fmaxf(brx-tlx, 0.0f), ih = fmaxf(bry-tly, 0.0f);
      float inter = iw*ih;
      float uni = bx.z*bx.w + tw*th - inter + 1e-16f;
      float iou2 = inter/uni;
      accIou = 1.0f - iou2*iou2;
      int mcls = (int)labS[mg*5];
      #pragma unroll 4
      for (int c = 0; c < NC_; c++) {
        float x = clsbase[(size_t)c * ai.hw];
        accCls += fmaxf(x,0.0f) - x*((c==mcls)?pi:0.0f) + __logf(1.0f + __expf(-fabsf(x)));
      }
    }
  }
  for (int o = 32; o > 0; o >>= 1) {
    accPf   += __shfl_down(accPf,   o, 64);
    accIou  += __shfl_down(accIou,  o, 64);
    accObjx += __shfl_down(accObjx, o, 64);
    accCls  += __shfl_down(accCls,  o, 64);
  }
  int lane = tid & 63, w = tid >> 6;
  if (lane == 0) { wpart[w][0]=accPf; wpart[w][1]=accIou; wpart[w][2]=accObjx; wpart[w][3]=accCls; }
  __syncthreads();
  if (tid == 0) {
    float s0=0.f,s1=0.f,s2=0.f,s3=0.f;
    for (int q=0;q<4;q++){ s0+=wpart[q][0]; s1+=wpart[q][1]; s2+=wpart[q][2]; s3+=wpart[q][3]; }
    if (s0!=0.f) atomicAdd(&acc[ACC_NUMFG], s0);
    if (s1!=0.f) atomicAdd(&acc[ACC_IOU],   s1);
    if (s2!=0.f) atomicAdd(&acc[ACC_OBJFG], s2);
    if (s3!=0.f) atomicAdd(&acc[ACC_CLS],   s3);
  }
}

__global__ void kE_final(const float* __restrict__ acc, float* __restrict__ out) {
  float nf = fmaxf(acc[ACC_NUMFG], 1.0f);
  out[0] = (5.0f*acc[ACC_IOU] + (acc[ACC_OBJ0] - acc[ACC_OBJFG]) + acc[ACC_CLS]) / nf;
}

extern "C" void kernel_launch(void* const* d_in, const int* in_sizes, int n_in,
                              void* d_out, int out_size, void* d_ws, size_t ws_size,
                              hipStream_t stream)
{
  const float* o0 = (const float*)d_in[0];
  const float* o1 = (const float*)d_in[1];
  const float* o2 = (const float*)d_in[2];
  const float* labels = (const float*)d_in[3];
  char* w = (char*)d_ws;
  size_t off = 0;
  auto alloc = [&](size_t bytes) -> void* {
    void* p = w + off; off += (bytes + 255) & ~(size_t)255; return p;
  };
  float4* cBox  = (float4*)alloc(sizeof(float4)*(size_t)B_*A_);
  float4* cMeta = (float4*)alloc(sizeof(float4)*(size_t)B_*A_);
  float4* cPack = (float4*)alloc(sizeof(float4)*(size_t)B_*A_);
  float*  thrw  = (float*) alloc(sizeof(float)*(size_t)B_*G_);
  int*    ncand = (int*)   alloc(sizeof(int)*B_);
  float*  acc   = (float*) alloc(sizeof(float)*8);

  hipMemsetAsync(ncand, 0, sizeof(int)*B_, stream);
  hipMemsetAsync(acc, 0, sizeof(float)*8, stream);

  dim3 grdA((A_+255)/256, B_);
  kA_decode<<<grdA, 256, 0, stream>>>(o0,o1,o2,labels,cBox,cMeta,ncand,acc);
  kS_ssum<<<grdA, 256, 0, stream>>>(o0,o1,o2,cMeta,ncand,cPack);
  kB_thresh<<<dim3(G_,B_), 256, 0, stream>>>(o0,o1,o2,labels,cBox,cPack,ncand,thrw);
  kC_loss<<<grdA, 256, 0, stream>>>(o0,o1,o2,labels,cBox,cPack,ncand,thrw,acc);
  kE_final<<<1,1,0,stream>>>(acc, (float*)d_out);
}

// Round 4
// 202.799 us; speedup vs baseline: 2.3782x; 1.2155x over previous
//
#include <hip/hip_runtime.h>
#include <math.h>

#define B_  32
#define A_  8400
#define G_  50
#define NC_ 80
#define CLIPHI ((float)(1.0 - 1e-6))

// padded accumulator slots (32 floats = 128 B apart)
#define ACC_NUMFG 0
#define ACC_IOU   32
#define ACC_OBJ0  64
#define ACC_OBJFG 96
#define ACC_CLS   128

struct AInfo { int lvl; int within; int w; int hw; float s; int x; int y; };

__device__ __forceinline__ AInfo anchor_info(int a) {
  AInfo r;
  if (a < 6400)      { r.lvl = 0; r.within = a;        r.w = 80; r.hw = 6400; r.s = 8.0f;  }
  else if (a < 8000) { r.lvl = 1; r.within = a - 6400; r.w = 40; r.hw = 1600; r.s = 16.0f; }
  else               { r.lvl = 2; r.within = a - 8000; r.w = 20; r.hw = 400;  r.s = 32.0f; }
  r.x = r.within % r.w; r.y = r.within / r.w;
  return r;
}

__device__ __forceinline__ const float* lvl_base(const float* o0, const float* o1,
                                                 const float* o2, int lvl) {
  return lvl == 0 ? o0 : (lvl == 1 ? o1 : o2);
}

// Inline cost: computed exactly once per (g,cand) pair (in kB), stored, re-read by kC.
__device__ __forceinline__ float2 cost_iou(
    float gx, float gy, float gw, float gh,
    float fx, float fy, float st,
    float4 bx, float ssum, float sobj, float clsv)
{
  float cx = (fx + 0.5f) * st;
  float cy = (fy + 0.5f) * st;
  bool in_box = (cx > gx - 0.5f*gw) && (cx < gx + 0.5f*gw) &&
                (cy > gy - 0.5f*gh) && (cy < gy + 0.5f*gh);
  float rs = 2.5f * st;
  bool in_ctr = (fabsf(cx - gx) < rs) && (fabsf(cy - gy) < rs);
  bool geom = in_box && in_ctr;
  float tlx = fmaxf(gx - gw*0.5f, bx.x - bx.z*0.5f);
  float tly = fmaxf(gy - gh*0.5f, bx.y - bx.w*0.5f);
  float brx = fminf(gx + gw*0.5f, bx.x + bx.z*0.5f);
  float bry = fminf(gy + gh*0.5f, bx.y + bx.w*0.5f);
  bool en = (tlx < brx) && (tly < bry);
  float inter = en ? (brx - tlx) * (bry - tly) : 0.0f;
  float iou = inter / (gw*gh + bx.z*bx.w - inter + 1e-12f);
  float iou_cost = -__logf(iou + 1e-8f);
  float sc = 1.0f / (1.0f + __expf(-clsv));
  float p = sqrtf(sc * sobj);
  p = fminf(fmaxf(p, 1e-7f), CLIPHI);
  float cls_cost = -__logf(p) + __logf(1.0f - p) - ssum;
  float cost = cls_cost + 3.0f * iou_cost;
  if (!geom) cost += 100000.0f;
  return make_float2(cost, iou);
}

// kA: decode + obj bce(x,0) + fg test + ssum (masked, 8 chains) + wave-aggregated
// compaction. Reads the entire 91 MB input once, coalesced.
__global__ __launch_bounds__(256)
void kA(const float* __restrict__ o0, const float* __restrict__ o1,
        const float* __restrict__ o2, const float* __restrict__ labels,
        float4* __restrict__ cBox, float4* __restrict__ cPack,
        int* __restrict__ ncandP, float* __restrict__ accP, int PAD)
{
  __shared__ float gl[G_], gr[G_], gtt[G_], gbb[G_], gcx[G_], gcy[G_];
  __shared__ int vflag[G_];
  __shared__ int nvgS;
  __shared__ float wsum[4];
  int b = blockIdx.y;
  int tid = threadIdx.x;
  if (tid < G_) {
    const float* L = labels + (size_t)b*G_*5 + tid*5;
    float l0=L[0], gx=L[1], gy=L[2], gw=L[3], gh=L[4];
    vflag[tid] = ((l0+gx+gy+gw+gh) > 0.0f) ? 1 : 0;
    gl[tid] = gx - 0.5f*gw; gr[tid] = gx + 0.5f*gw;
    gtt[tid] = gy - 0.5f*gh; gbb[tid] = gy + 0.5f*gh;
    gcx[tid] = gx; gcy[tid] = gy;
  }
  __syncthreads();
  if (tid == 0) {
    int n = 0;
    for (int g = 0; g < G_; g++) {
      if (vflag[g]) {
        gl[n]=gl[g]; gr[n]=gr[g]; gtt[n]=gtt[g]; gbb[n]=gbb[g];
        gcx[n]=gcx[g]; gcy[n]=gcy[g]; n++;
      }
    }
    nvgS = n;
  }
  __syncthreads();
  int nvg = nvgS;
  int a = blockIdx.x*256 + tid;
  bool inr = (a < A_);
  float objbce = 0.0f, v4 = 0.0f, so = 0.0f, ss = 0.0f;
  float4 bx = make_float4(0.f,0.f,0.f,0.f);
  bool anyfg = false;
  AInfo ai; const float* base = nullptr;
  if (inr) {
    ai = anchor_info(a);
    base = lvl_base(o0,o1,o2,ai.lvl) + (size_t)b*85*ai.hw + ai.within;
    float v0 = base[0];
    float v1 = base[(size_t)1*ai.hw];
    float v2 = base[(size_t)2*ai.hw];
    float v3 = base[(size_t)3*ai.hw];
    v4 = base[(size_t)4*ai.hw];
    bx.x = (v0 + (float)ai.x) * ai.s;
    bx.y = (v1 + (float)ai.y) * ai.s;
    bx.z = __expf(v2) * ai.s;
    bx.w = __expf(v3) * ai.s;
    objbce = fmaxf(v4, 0.0f) + __logf(1.0f + __expf(-fabsf(v4)));
    float cx = ((float)ai.x + 0.5f) * ai.s;
    float cy = ((float)ai.y + 0.5f) * ai.s;
    float rs = 2.5f * ai.s;
    for (int k = 0; k < nvg; k++) {
      bool in_box = (cx > gl[k]) && (cx < gr[k]) && (cy > gtt[k]) && (cy < gbb[k]);
      bool in_ctr = (fabsf(cx - gcx[k]) < rs) && (fabsf(cy - gcy[k]) < rs);
      if (in_box || in_ctr) { anyfg = true; break; }
    }
    so = 1.0f / (1.0f + __expf(-v4));
  }
  if (anyfg) {
    const float* q = base + (size_t)5*ai.hw;
    float s0=0,s1=0,s2=0,s3=0,s4=0,s5=0,s6=0,s7=0;
    for (int c = 0; c < NC_; c += 8) {
      float x0 = q[(size_t)(c+0)*ai.hw];
      float x1 = q[(size_t)(c+1)*ai.hw];
      float x2 = q[(size_t)(c+2)*ai.hw];
      float x3 = q[(size_t)(c+3)*ai.hw];
      float x4 = q[(size_t)(c+4)*ai.hw];
      float x5 = q[(size_t)(c+5)*ai.hw];
      float x6 = q[(size_t)(c+6)*ai.hw];
      float x7 = q[(size_t)(c+7)*ai.hw];
      #define TERM(xx, ss_) { \
        float sc = 1.0f/(1.0f+__expf(-(xx))); \
        float p = sqrtf(sc*so); \
        p = fminf(fmaxf(p,1e-7f), CLIPHI); \
        ss_ += __logf(1.0f - p); }
      TERM(x0,s0) TERM(x1,s1) TERM(x2,s2) TERM(x3,s3)
      TERM(x4,s4) TERM(x5,s5) TERM(x6,s6) TERM(x7,s7)
      #undef TERM
    }
    ss = ((s0+s1)+(s2+s3)) + ((s4+s5)+(s6+s7));
  }
  // block-reduce obj bce -> 1 atomic per block (padded slot)
  float v = objbce;
  for (int o = 32; o > 0; o >>= 1) v += __shfl_down(v, o, 64);
  if ((tid & 63) == 0) wsum[tid >> 6] = v;
  __syncthreads();
  if (tid == 0) atomicAdd(&accP[ACC_OBJ0], wsum[0]+wsum[1]+wsum[2]+wsum[3]);
  // wave-aggregated compaction: ONE atomic per wave, to a per-image padded counter.
  unsigned long long mm = __ballot(anyfg);
  int lane = tid & 63;
  int cnt = __popcll(mm);
  int b0 = 0;
  if (lane == 0 && cnt) b0 = atomicAdd(&ncandP[b*32], cnt);
  b0 = __shfl(b0, 0, 64);
  if (anyfg) {
    int pos = b0 + __popcll(mm & ((1ull << lane) - 1ull));
    if (pos < PAD) {
      cBox[b*A_ + pos]  = bx;
      cPack[b*A_ + pos] = make_float4(ss, so, __int_as_float(a), v4);
    }
  }
}

// kB: per (gt,image) block — compute the cost row ONCE (store to costM),
// top-10 iou -> dyn_k, top-10 cost -> threshold.
__global__ __launch_bounds__(256)
void kB(const float* __restrict__ o0, const float* __restrict__ o1,
        const float* __restrict__ o2, const float* __restrict__ labels,
        const float4* __restrict__ cBox, const float4* __restrict__ cPack,
        const int* __restrict__ ncandP, float* __restrict__ thrw,
        float* __restrict__ costM, int PAD)
{
  __shared__ float sh[256*10];
  __shared__ int s_dk;
  int g = blockIdx.x, b = blockIdx.y;
  int tid = threadIdx.x;
  const float* L = labels + (size_t)(b*G_ + g)*5;
  float l0=L[0], gx=L[1], gy=L[2], gw=L[3], gh=L[4];
  bool gvalid = (l0+gx+gy+gw+gh) > 0.0f;
  if (!gvalid) { if (tid==0) thrw[b*G_+g] = -3.0e38f; return; }
  int gcls = (int)l0;
  int nc = ncandP[b*32]; if (nc > PAD) nc = PAD;
  float* row = costM + ((size_t)b*G_ + g)*(size_t)PAD;
  float ti[10], tc[10];
  #pragma unroll
  for (int j=0;j<10;j++){ ti[j]=0.0f; tc[j]=3e38f; }
  for (int i = tid; i < nc; i += 256) {
    float4 bx = cBox[b*A_ + i];
    float4 pk = cPack[b*A_ + i];
    int a = __float_as_int(pk.z);
    AInfo ai = anchor_info(a);
    float clsv = lvl_base(o0,o1,o2,ai.lvl)[(size_t)(b*85 + 5 + gcls)*ai.hw + ai.within];
    float2 ci = cost_iou(gx,gy,gw,gh,(float)ai.x,(float)ai.y,ai.s,
                         bx, pk.x, pk.y, clsv);
    row[i] = ci.x;
    float v = ci.y;
    if (v > ti[9]) {
      #pragma unroll
      for (int j=0;j<10;j++){ float o=ti[j]; bool t=v>o; ti[j]=t?v:o; v=t?o:v; }
    }
    float c = ci.x;
    if (c < tc[9]) {
      #pragma unroll
      for (int j=0;j<10;j++){ float o=tc[j]; bool t=c<o; tc[j]=t?c:o; c=t?o:c; }
    }
  }
  // merge top-10 IoU (descending)
  #pragma unroll
  for (int j=0;j<10;j++) sh[tid*10+j] = ti[j];
  __syncthreads();
  for (int str=128; str>0; str>>=1) {
    if (tid < str) {
      float out[10]; int i=0, jj=0;
      float* Aa = &sh[tid*10]; float* Bb = &sh[(tid+str)*10];
      #pragma unroll
      for (int k=0;k<10;k++){ float va=Aa[i], vb=Bb[jj]; bool t=(va>=vb); out[k]=t?va:vb; if(t)i++; else jj++; }
      #pragma unroll
      for (int k=0;k<10;k++) Aa[k]=out[k];
    }
    __syncthreads();
  }
  if (tid==0) {
    float s10=0.0f;
    #pragma unroll
    for (int j=0;j<10;j++) s10 += sh[j];
    int dk = (int)s10; if (dk<1) dk=1; if (dk>10) dk=10;
    s_dk = dk;
  }
  __syncthreads();
  // merge top-10 smallest cost (ascending)
  #pragma unroll
  for (int j=0;j<10;j++) sh[tid*10+j] = tc[j];
  __syncthreads();
  for (int str=128; str>0; str>>=1) {
    if (tid < str) {
      float out[10]; int i=0, jj=0;
      float* Aa = &sh[tid*10]; float* Bb = &sh[(tid+str)*10];
      #pragma unroll
      for (int k=0;k<10;k++){ float va=Aa[i], vb=Bb[jj]; bool t=(va<=vb); out[k]=t?va:vb; if(t)i++; else jj++; }
      #pragma unroll
      for (int k=0;k<10;k++) Aa[k]=out[k];
    }
    __syncthreads();
  }
  if (tid==0) thrw[b*G_+g] = sh[s_dk-1];
}

// kC: thread per candidate; reads STORED costs (exact parity with kB) with 20
// independent coalesced loads; match resolution + all fg losses.
__global__ __launch_bounds__(256)
void kC(const float* __restrict__ o0, const float* __restrict__ o1,
        const float* __restrict__ o2, const float* __restrict__ labels,
        const float4* __restrict__ cBox, const float4* __restrict__ cPack,
        const int* __restrict__ ncandP, const float* __restrict__ thrw,
        const float* __restrict__ costM, float* __restrict__ accP, int PAD)
{
  int b = blockIdx.y;
  int nc = ncandP[b*32]; if (nc > PAD) nc = PAD;
  if (blockIdx.x*256 >= nc) return;
  __shared__ float labS[G_*5];
  __shared__ float thrS[G_];
  __shared__ int vgIdx[G_];
  __shared__ int nvgS;
  __shared__ float wpart[4][4];
  int tid = threadIdx.x;
  for (int i = tid; i < G_*5; i += 256) labS[i] = labels[(size_t)b*G_*5 + i];
  if (tid < G_) thrS[tid] = thrw[b*G_ + tid];
  __syncthreads();
  if (tid == 0) {
    int n = 0;
    for (int g = 0; g < G_; g++) {
      float s5 = labS[g*5]+labS[g*5+1]+labS[g*5+2]+labS[g*5+3]+labS[g*5+4];
      if (s5 > 0.0f) vgIdx[n++] = g;
    }
    nvgS = n;
  }
  __syncthreads();
  int nvg = nvgS;
  int i = blockIdx.x*256 + tid;
  float accPf=0.f, accIou=0.f, accObjx=0.f, accCls=0.f;
  if (i < nc) {
    const float* cm = costM + (size_t)b*G_*(size_t)PAD + i;
    float minc = 3e38f; int ming = 0;
    int cnt = 0; int firstg = -1;
    for (int k = 0; k < nvg; k++) {
      int g = vgIdx[k];
      float c = cm[(size_t)g*PAD];
      if (c < minc) { minc = c; ming = g; }
      if (c <= thrS[g]) { cnt++; if (firstg < 0) firstg = g; }
    }
    int mg = -1;
    if (cnt == 1)     mg = firstg;
    else if (cnt > 1) { if (minc <= thrS[ming]) mg = ming; }
    if (mg >= 0) {
      float4 bx = cBox[b*A_ + i];
      float4 pk = cPack[b*A_ + i];
      accPf = 1.0f;
      accObjx = pk.w;
      float tx=labS[mg*5+1], ty=labS[mg*5+2], tw=labS[mg*5+3], th=labS[mg*5+4];
      // piou: en-style pairwise iou (feeds cls target)
      float tlx = fmaxf(tx - tw*0.5f, bx.x - bx.z*0.5f);
      float tly = fmaxf(ty - th*0.5f, bx.y - bx.w*0.5f);
      float brx = fminf(tx + tw*0.5f, bx.x + bx.z*0.5f);
      float bry = fminf(ty + th*0.5f, bx.y + bx.w*0.5f);
      bool en = (tlx < brx) && (tly < bry);
      float inter_p = en ? (brx - tlx) * (bry - tly) : 0.0f;
      float pi = inter_p / (tw*th + bx.z*bx.w - inter_p + 1e-12f);
      // loss iou: clip-style
      float iw = fmaxf(brx-tlx, 0.0f), ih = fmaxf(bry-tly, 0.0f);
      float inter = iw*ih * (en ? 1.0f : 0.0f);
      float uni = bx.z*bx.w + tw*th - inter + 1e-16f;
      float iou2 = inter/uni;
      accIou = 1.0f - iou2*iou2;
      int mcls = (int)labS[mg*5];
      int a = __float_as_int(pk.z);
      AInfo ai = anchor_info(a);
      const float* clsbase = lvl_base(o0,o1,o2,ai.lvl) + (size_t)(b*85 + 5)*ai.hw + ai.within;
      #pragma unroll 4
      for (int c = 0; c < NC_; c++) {
        float x = clsbase[(size_t)c * ai.hw];
        accCls += fmaxf(x,0.0f) - x*((c==mcls)?pi:0.0f) + __logf(1.0f + __expf(-fabsf(x)));
      }
    }
  }
  for (int o = 32; o > 0; o >>= 1) {
    accPf   += __shfl_down(accPf,   o, 64);
    accIou  += __shfl_down(accIou,  o, 64);
    accObjx += __shfl_down(accObjx, o, 64);
    accCls  += __shfl_down(accCls,  o, 64);
  }
  int lane = tid & 63, w = tid >> 6;
  if (lane == 0) { wpart[w][0]=accPf; wpart[w][1]=accIou; wpart[w][2]=accObjx; wpart[w][3]=accCls; }
  __syncthreads();
  if (tid == 0) {
    float s0=0.f,s1=0.f,s2=0.f,s3=0.f;
    for (int q=0;q<4;q++){ s0+=wpart[q][0]; s1+=wpart[q][1]; s2+=wpart[q][2]; s3+=wpart[q][3]; }
    if (s0!=0.f) atomicAdd(&accP[ACC_NUMFG], s0);
    if (s1!=0.f) atomicAdd(&accP[ACC_IOU],   s1);
    if (s2!=0.f) atomicAdd(&accP[ACC_OBJFG], s2);
    if (s3!=0.f) atomicAdd(&accP[ACC_CLS],   s3);
  }
}

__global__ void kE(const float* __restrict__ accP, float* __restrict__ out) {
  float nf = fmaxf(accP[ACC_NUMFG], 1.0f);
  out[0] = (5.0f*accP[ACC_IOU] + (accP[ACC_OBJ0] - accP[ACC_OBJFG]) + accP[ACC_CLS]) / nf;
}

extern "C" void kernel_launch(void* const* d_in, const int* in_sizes, int n_in,
                              void* d_out, int out_size, void* d_ws, size_t ws_size,
                              hipStream_t stream)
{
  const float* o0 = (const float*)d_in[0];
  const float* o1 = (const float*)d_in[1];
  const float* o2 = (const float*)d_in[2];
  const float* labels = (const float*)d_in[3];
  char* w = (char*)d_ws;
  size_t off = 0;
  auto alloc = [&](size_t bytes) -> void* {
    void* p = w + off; off += (bytes + 255) & ~(size_t)255; return p;
  };
  float4* cBox  = (float4*)alloc(sizeof(float4)*(size_t)B_*A_);
  float4* cPack = (float4*)alloc(sizeof(float4)*(size_t)B_*A_);
  float*  thrw  = (float*) alloc(sizeof(float)*(size_t)B_*G_);
  int*    ncandP= (int*)   alloc(sizeof(int)*B_*32);
  float*  accP  = (float*) alloc(sizeof(float)*256);
  // cost matrix: PAD chosen from remaining workspace, capped at 8448 (>= A_).
  size_t avail = (ws_size > off) ? (ws_size - off) : 0;
  size_t padMax = avail / ((size_t)B_*G_*sizeof(float));
  int PAD = (int)(padMax > 8448 ? 8448 : (padMax & ~(size_t)255));
  if (PAD < 256) PAD = 256;
  float* costM = (float*)alloc(sizeof(float)*(size_t)B_*G_*(size_t)PAD);

  hipMemsetAsync(ncandP, 0, sizeof(int)*B_*32, stream);
  hipMemsetAsync(accP, 0, sizeof(float)*256, stream);

  dim3 grdA((A_+255)/256, B_);
  kA<<<grdA, 256, 0, stream>>>(o0,o1,o2,labels,cBox,cPack,ncandP,accP,PAD);
  kB<<<dim3(G_,B_), 256, 0, stream>>>(o0,o1,o2,labels,cBox,cPack,ncandP,thrw,costM,PAD);
  kC<<<grdA, 256, 0, stream>>>(o0,o1,o2,labels,cBox,cPack,ncandP,thrw,costM,accP,PAD);
  kE<<<1,1,0,stream>>>(accP, (float*)d_out);
}